// Round 9
// baseline (969.193 us; speedup 1.0000x reference)
//
#include <hip/hip_runtime.h>

#define NN 50000
#define DD 128
#define EE 1600000
#define NBUK 196   // ceil(50000/256) buckets of 256 nodes

typedef unsigned int uint;
typedef unsigned short ushort;
typedef float floatx2 __attribute__((ext_vector_type(2)));  // clang vector: ok for nontemporal builtins

__device__ __forceinline__ ushort f2bf(float f) {
    uint u = __float_as_uint(f);
    u += 0x7fffu + ((u >> 16) & 1u);  // round-to-nearest-even
    return (ushort)(u >> 16);
}

// ---------------- f32 -> bf16 table conversion ----------------
__global__ void __launch_bounds__(256) f32_to_bf16_kernel(const float* __restrict__ in,
                                                          ushort* __restrict__ out, int n4) {
    int i = blockIdx.x * blockDim.x + threadIdx.x;
    if (i < n4) {
        float4 v = ((const float4*)in)[i];
        ushort4 o;
        o.x = f2bf(v.x);
        o.y = f2bf(v.y);
        o.z = f2bf(v.z);
        o.w = f2bf(v.w);
        ((ushort4*)out)[i] = o;
    }
}

// ---------------- bucketed CSR build ----------------
// bucket b = dst >> 8 (256 nodes per bucket)

__global__ void __launch_bounds__(1024) bucket_hist_kernel(const int* __restrict__ dst,
                                                           int* __restrict__ bcnt) {
    __shared__ int h[NBUK];
    int t = threadIdx.x;
    for (int i = t; i < NBUK; i += 1024) h[i] = 0;
    __syncthreads();
    for (int e = blockIdx.x * 1024 + t; e < EE; e += gridDim.x * 1024)
        atomicAdd(&h[dst[e] >> 8], 1);
    __syncthreads();
    for (int i = t; i < NBUK; i += 1024)
        if (h[i]) atomicAdd(&bcnt[i], h[i]);
}

// 1 block, 256 threads: exclusive scan of bcnt[256] (entries >= NBUK are zero)
__global__ void __launch_bounds__(256) bucket_scan_kernel(const int* __restrict__ bcnt,
                                                          int* __restrict__ bbase,
                                                          int* __restrict__ bcur) {
    int t = threadIdx.x, lane = t & 63, w = t >> 6;
    int v = bcnt[t];
    int inc = v;
#pragma unroll
    for (int off = 1; off < 64; off <<= 1) {
        int n = __shfl_up(inc, off);
        if (lane >= off) inc += n;
    }
    __shared__ int wsum[4];
    if (lane == 63) wsum[w] = inc;
    __syncthreads();
    int woff = 0;
#pragma unroll
    for (int i = 0; i < 4; ++i)
        if (i < w) woff += wsum[i];
    int ex = woff + inc - v;
    bbase[t] = ex;
    bcur[t] = ex;
}

// scatter edges into bucket-grouped packed array: u32 = (dst&255)<<16 | src
__global__ void __launch_bounds__(1024) bucket_scatter_kernel(const int* __restrict__ src,
                                                              const int* __restrict__ dst,
                                                              int* __restrict__ bcur,
                                                              uint* __restrict__ packed) {
    __shared__ int cnt[NBUK];
    __shared__ int base[NBUK];
    int t = threadIdx.x;
    long e0 = (long)blockIdx.x * 4096;
    for (int i = t; i < NBUK; i += 1024) cnt[i] = 0;
    __syncthreads();
    int b[4], off[4];
    uint pk[4];
#pragma unroll
    for (int u = 0; u < 4; ++u) {
        long e = e0 + u * 1024 + t;
        if (e < EE) {
            int d = dst[e];
            int s = src[e];
            b[u] = d >> 8;
            pk[u] = (uint)s | ((uint)(d & 255) << 16);
            off[u] = atomicAdd(&cnt[b[u]], 1);
        } else {
            b[u] = -1;
        }
    }
    __syncthreads();
    for (int i = t; i < NBUK; i += 1024) base[i] = cnt[i] ? atomicAdd(&bcur[i], cnt[i]) : 0;
    __syncthreads();
#pragma unroll
    for (int u = 0; u < 4; ++u)
        if (b[u] >= 0) packed[base[b[u]] + off[u]] = pk[u];
}

// one block per bucket: per-node degree hist + scan in LDS -> rowptr + sorted src (ushort)
__global__ void __launch_bounds__(1024) bucket_build_kernel(const uint* __restrict__ packed,
                                                            const int* __restrict__ bbase,
                                                            const int* __restrict__ bcnt,
                                                            int* __restrict__ rowptr,
                                                            ushort* __restrict__ sorted) {
    int b = blockIdx.x;
    int t = threadIdx.x;
    int ebeg = bbase[b], ecnt = bcnt[b];
    int node0 = b << 8;
    int nn = min(256, NN - node0);
    __shared__ int deg[256];
    __shared__ int cur[256];
    __shared__ int wsum[4];
    for (int i = t; i < 256; i += 1024) deg[i] = 0;
    __syncthreads();
    for (int i = t; i < ecnt; i += 1024) {
        uint p = packed[ebeg + i];
        atomicAdd(&deg[(p >> 16) & 255], 1);
    }
    __syncthreads();
    int lane = t & 63, w = t >> 6;
    int v = (t < 256) ? deg[t] : 0;
    int inc = v;
#pragma unroll
    for (int off = 1; off < 64; off <<= 1) {
        int n = __shfl_up(inc, off);
        if (lane >= off) inc += n;
    }
    if (t < 256 && lane == 63) wsum[w] = inc;
    __syncthreads();
    if (t < 256) {
        int woff = 0;
#pragma unroll
        for (int i = 0; i < 4; ++i)
            if (i < w) woff += wsum[i];
        int ex = woff + inc - v;
        if (t < nn) rowptr[node0 + t] = ebeg + ex;
        cur[t] = ebeg + ex;
    }
    if (b == NBUK - 1 && t == 0) rowptr[NN] = ebeg + ecnt;
    __syncthreads();
    for (int i = t; i < ecnt; i += 1024) {
        uint p = packed[ebeg + i];
        int pos = atomicAdd(&cur[(p >> 16) & 255], 1);
        sorted[pos] = (ushort)(p & 0xFFFFu);
    }
}

// ---------------- column-sliced mean aggregation ----------------
// pass p covers cols [32p, 32p+32): slice = 3.2MB -> fits per-XCD L2.
// 16 lanes per dst row (lane16 -> one uint = 2 bf16 cols), 4 rows per wave.
__global__ void __launch_bounds__(256) agg_pass_kernel(const uint* __restrict__ xu,
                                                       const int* __restrict__ rowptr,
                                                       const ushort* __restrict__ srcs,
                                                       float* __restrict__ out, int p) {
    int gid = blockIdx.x * 256 + threadIdx.x;
    int lane16 = threadIdx.x & 15;
    int row = gid >> 4;
    if (row >= NN) return;
    int beg = rowptr[row], end = rowptr[row + 1];
    const uint* bp = xu + p * 16 + lane16;
    float ax = 0.f, ay = 0.f;
    int j = beg;
    for (; j + 4 <= end; j += 4) {
        int s0 = (int)__builtin_nontemporal_load(srcs + j);
        int s1 = (int)__builtin_nontemporal_load(srcs + j + 1);
        int s2 = (int)__builtin_nontemporal_load(srcs + j + 2);
        int s3 = (int)__builtin_nontemporal_load(srcs + j + 3);
        uint v0 = bp[s0 * 64];
        uint v1 = bp[s1 * 64];
        uint v2 = bp[s2 * 64];
        uint v3 = bp[s3 * 64];
        ax += __uint_as_float(v0 << 16) + __uint_as_float(v1 << 16) +
              __uint_as_float(v2 << 16) + __uint_as_float(v3 << 16);
        ay += __uint_as_float(v0 & 0xffff0000u) + __uint_as_float(v1 & 0xffff0000u) +
              __uint_as_float(v2 & 0xffff0000u) + __uint_as_float(v3 & 0xffff0000u);
    }
    for (; j < end; ++j) {
        int s = (int)__builtin_nontemporal_load(srcs + j);
        uint v = bp[s * 64];
        ax += __uint_as_float(v << 16);
        ay += __uint_as_float(v & 0xffff0000u);
    }
    float inv = (end > beg) ? 1.0f / (float)(end - beg) : 0.0f;
    floatx2 r;
    r.x = ax * inv;
    r.y = ay * inv;
    __builtin_nontemporal_store(r, reinterpret_cast<floatx2*>(
                                       out + (size_t)row * DD + p * 32 + lane16 * 2));
}

// ---------------- fused SAGE linear: out = [relu](A1@W1 + A2@W2 + b) ----------------
// MODE 0: f32 out + relu | MODE 1: bf16 out + relu | MODE 2: fused final linear -> [N,2] f32
template <int MODE>
__global__ void __launch_bounds__(256) sage_gemm_kernel(
    const float* __restrict__ A1, const float* __restrict__ W1, const float* __restrict__ A2,
    const float* __restrict__ W2, const float* __restrict__ bias, const float* __restrict__ Wf,
    const float* __restrict__ bf, void* __restrict__ out) {
    __shared__ float a1s[16][DD];
    __shared__ float a2s[16][DD];
    int t = threadIdx.x;
    int c = t & 127;
    int g = t >> 7;
    int row0 = blockIdx.x * 16;
    {
        const float4* A1v = (const float4*)(A1 + (size_t)row0 * DD);
        const float4* A2v = (const float4*)(A2 + (size_t)row0 * DD);
        float4* s1 = (float4*)a1s;
        float4* s2 = (float4*)a2s;
#pragma unroll
        for (int i = 0; i < 2; ++i) {
            s1[t + i * 256] = A1v[t + i * 256];
            s2[t + i * 256] = A2v[t + i * 256];
        }
    }
    __syncthreads();
    float acc[8] = {0.f, 0.f, 0.f, 0.f, 0.f, 0.f, 0.f, 0.f};
    for (int k = 0; k < DD; k += 4) {
        float4 a1[8], a2[8];
#pragma unroll
        for (int r = 0; r < 8; ++r) {
            a1[r] = *(const float4*)&a1s[g * 8 + r][k];
            a2[r] = *(const float4*)&a2s[g * 8 + r][k];
        }
        float w10 = W1[(k + 0) * DD + c], w11 = W1[(k + 1) * DD + c];
        float w12 = W1[(k + 2) * DD + c], w13 = W1[(k + 3) * DD + c];
        float w20 = W2[(k + 0) * DD + c], w21 = W2[(k + 1) * DD + c];
        float w22 = W2[(k + 2) * DD + c], w23 = W2[(k + 3) * DD + c];
#pragma unroll
        for (int r = 0; r < 8; ++r) {
            acc[r] += a1[r].x * w10 + a1[r].y * w11 + a1[r].z * w12 + a1[r].w * w13;
            acc[r] += a2[r].x * w20 + a2[r].y * w21 + a2[r].z * w22 + a2[r].w * w23;
        }
    }
    float b = bias[c];
    if (MODE == 2) {
        float wf0 = Wf[c * 2 + 0], wf1 = Wf[c * 2 + 1];
        __shared__ float red[4][8][2];
        int w = t >> 6, lane = t & 63;
#pragma unroll
        for (int r = 0; r < 8; ++r) {
            float v = acc[r] + b;
            float p0 = v * wf0, p1 = v * wf1;
#pragma unroll
            for (int off = 32; off; off >>= 1) {
                p0 += __shfl_down(p0, off);
                p1 += __shfl_down(p1, off);
            }
            if (lane == 0) {
                red[w][r][0] = p0;
                red[w][r][1] = p1;
            }
        }
        __syncthreads();
        if (t < 32) {
            int gg = t >> 4;
            int rr = (t >> 1) & 7;
            int o = t & 1;
            float v = red[gg * 2][rr][o] + red[gg * 2 + 1][rr][o] + bf[o];
            ((float*)out)[(size_t)(row0 + gg * 8 + rr) * 2 + o] = v;
        }
    } else {
#pragma unroll
        for (int r = 0; r < 8; ++r) {
            float v = fmaxf(acc[r] + b, 0.f);
            size_t idx = (size_t)(row0 + g * 8 + r) * DD + c;
            if (MODE == 0)
                ((float*)out)[idx] = v;
            else
                ((ushort*)out)[idx] = f2bf(v);
        }
    }
}

extern "C" void kernel_launch(void* const* d_in, const int* in_sizes, int n_in,
                              void* d_out, int out_size, void* d_ws, size_t ws_size,
                              hipStream_t stream) {
    const float* x_student = (const float*)d_in[0];
    const float* x_studies = (const float*)d_in[1];
    const int* ei_s2st = (const int*)d_in[2];
    const int* ei_st2s = (const int*)d_in[3];
    const float* l1_st_Wl = (const float*)d_in[4];
    const float* l1_st_b = (const float*)d_in[5];
    const float* l1_st_Wr = (const float*)d_in[6];
    const float* l1_s_Wl = (const float*)d_in[7];
    const float* l1_s_b = (const float*)d_in[8];
    const float* l1_s_Wr = (const float*)d_in[9];
    const float* l2_st_Wl = (const float*)d_in[10];
    const float* l2_st_b = (const float*)d_in[11];
    const float* l2_st_Wr = (const float*)d_in[12];
    const float* lin_W = (const float*)d_in[16];
    const float* lin_b = (const float*)d_in[17];
    float* out = (float*)d_out;

    // workspace layout
    char* ws = (char*)d_ws;
    float* agg = (float*)ws;                              // N*D f32
    float* hst = agg + (size_t)NN * DD;                   // N*D f32
    uint* packed = (uint*)(hst + (size_t)NN * DD);        // E u32 (transient, shared a/b)
    int* rowptr_a = (int*)(packed + EE);                  // N+1
    int* rowptr_b = rowptr_a + (NN + 1);                  // N+1
    int* bcnt_a = rowptr_b + (NN + 1);                    // 256
    int* bcnt_b = bcnt_a + 256;                           // 256
    int* bbase_a = bcnt_b + 256;                          // 256
    int* bcur_a = bbase_a + 256;                          // 256
    int* bbase_b = bcur_a + 256;                          // 256
    int* bcur_b = bbase_b + 256;                          // 256
    ushort* xstu_bf = (ushort*)(bcur_b + 256);            // N*D bf16
    ushort* xsts_bf = xstu_bf + (size_t)NN * DD;          // N*D bf16
    ushort* hs_bf = xsts_bf + (size_t)NN * DD;            // N*D bf16
    ushort* sorted_a = hs_bf + (size_t)NN * DD;           // E ushort
    ushort* sorted_b = sorted_a + EE;                     // E ushort

    const int* src_a = ei_s2st;       // s2st: src=student
    const int* dst_a = ei_s2st + EE;  // dst=studies
    const int* src_b = ei_st2s;       // st2s: src=studies
    const int* dst_b = ei_st2s + EE;  // dst=student

    const int cvGrid = (NN * DD / 4 + 255) / 256;
    const int scGrid = (EE + 4095) / 4096;  // 391
    const int aggGrid = (NN * 16 + 255) / 256;  // 3125
    const int gemmGrid = NN / 16;               // 3125

    // 0. bf16 feature tables
    f32_to_bf16_kernel<<<cvGrid, 256, 0, stream>>>(x_student, xstu_bf, NN * DD / 4);
    f32_to_bf16_kernel<<<cvGrid, 256, 0, stream>>>(x_studies, xsts_bf, NN * DD / 4);

    // 1. bucketed CSR build, edge type a then b (shared packed buffer)
    (void)hipMemsetAsync(bcnt_a, 0, 2 * 256 * sizeof(int), stream);
    bucket_hist_kernel<<<256, 1024, 0, stream>>>(dst_a, bcnt_a);
    bucket_hist_kernel<<<256, 1024, 0, stream>>>(dst_b, bcnt_b);
    bucket_scan_kernel<<<1, 256, 0, stream>>>(bcnt_a, bbase_a, bcur_a);
    bucket_scan_kernel<<<1, 256, 0, stream>>>(bcnt_b, bbase_b, bcur_b);
    bucket_scatter_kernel<<<scGrid, 1024, 0, stream>>>(src_a, dst_a, bcur_a, packed);
    bucket_build_kernel<<<NBUK, 1024, 0, stream>>>(packed, bbase_a, bcnt_a, rowptr_a, sorted_a);
    bucket_scatter_kernel<<<scGrid, 1024, 0, stream>>>(src_b, dst_b, bcur_b, packed);
    bucket_build_kernel<<<NBUK, 1024, 0, stream>>>(packed, bbase_b, bcnt_b, rowptr_b, sorted_b);

    // 2. layer 1: h_st = relu(mean_s2st(x_student)@Wl + b + x_studies@Wr)  -> f32
    for (int p = 0; p < 4; ++p)
        agg_pass_kernel<<<aggGrid, 256, 0, stream>>>((const uint*)xstu_bf, rowptr_a, sorted_a,
                                                     agg, p);
    sage_gemm_kernel<0><<<gemmGrid, 256, 0, stream>>>(agg, l1_st_Wl, x_studies, l1_st_Wr,
                                                      l1_st_b, nullptr, nullptr, hst);
    //    h_s = relu(mean_st2s(x_studies)@Wl + b + x_student@Wr)  -> bf16
    for (int p = 0; p < 4; ++p)
        agg_pass_kernel<<<aggGrid, 256, 0, stream>>>((const uint*)xsts_bf, rowptr_b, sorted_b,
                                                     agg, p);
    sage_gemm_kernel<1><<<gemmGrid, 256, 0, stream>>>(agg, l1_s_Wl, x_student, l1_s_Wr,
                                                      l1_s_b, nullptr, nullptr, hs_bf);

    // 3. layer 2 + fused final linear -> out [N,2]
    for (int p = 0; p < 4; ++p)
        agg_pass_kernel<<<aggGrid, 256, 0, stream>>>((const uint*)hs_bf, rowptr_a, sorted_a,
                                                     agg, p);
    sage_gemm_kernel<2><<<gemmGrid, 256, 0, stream>>>(agg, l2_st_Wl, hst, l2_st_Wr,
                                                      l2_st_b, lin_W, lin_b, out);
}

// Round 12
// 504.411 us; speedup vs baseline: 1.9214x; 1.9214x over previous
//
#include <hip/hip_runtime.h>

#define NN 50000
#define DD 128
#define EE 1600000
#define NBUK 196   // ceil(50000/256) buckets of 256 nodes

typedef unsigned int uint;
typedef unsigned short ushort;
typedef __attribute__((ext_vector_type(8))) short bf16x8;  // 8 bf16 = 4 VGPRs (MFMA A/B frag)
typedef __attribute__((ext_vector_type(4))) float f32x4;   // MFMA C/D frag

__device__ __forceinline__ ushort f2bf(float f) {
    uint u = __float_as_uint(f);
    u += 0x7fffu + ((u >> 16) & 1u);  // round-to-nearest-even
    return (ushort)(u >> 16);
}

// ---------------- f32 -> bf16 table conversion ----------------
__global__ void __launch_bounds__(256) f32_to_bf16_kernel(const float* __restrict__ in,
                                                          ushort* __restrict__ out, int n4) {
    int i = blockIdx.x * blockDim.x + threadIdx.x;
    if (i < n4) {
        float4 v = ((const float4*)in)[i];
        ushort4 o;
        o.x = f2bf(v.x);
        o.y = f2bf(v.y);
        o.z = f2bf(v.z);
        o.w = f2bf(v.w);
        ((ushort4*)out)[i] = o;
    }
}

// W [k][c] f32  ->  Wt [c][k] bf16 (transposed so B-frag reads are 16B contiguous)
__global__ void __launch_bounds__(256) wconv_kernel(const float* __restrict__ w,
                                                    ushort* __restrict__ wt) {
    int idx = blockIdx.x * 256 + threadIdx.x;  // 16384 threads
    int c = idx >> 7, k = idx & 127;
    wt[idx] = f2bf(w[k * DD + c]);
}

// ---------------- bucketed CSR build ----------------
// bucket b = dst >> 8 (256 nodes per bucket)

__global__ void __launch_bounds__(1024) bucket_hist_kernel(const int* __restrict__ dst,
                                                           int* __restrict__ bcnt) {
    __shared__ int h[NBUK];
    int t = threadIdx.x;
    for (int i = t; i < NBUK; i += 1024) h[i] = 0;
    __syncthreads();
    for (int e = blockIdx.x * 1024 + t; e < EE; e += gridDim.x * 1024)
        atomicAdd(&h[dst[e] >> 8], 1);
    __syncthreads();
    for (int i = t; i < NBUK; i += 1024)
        if (h[i]) atomicAdd(&bcnt[i], h[i]);
}

// 1 block, 256 threads: exclusive scan of bcnt[256] (entries >= NBUK are zero)
__global__ void __launch_bounds__(256) bucket_scan_kernel(const int* __restrict__ bcnt,
                                                          int* __restrict__ bbase,
                                                          int* __restrict__ bcur) {
    int t = threadIdx.x, lane = t & 63, w = t >> 6;
    int v = bcnt[t];
    int inc = v;
#pragma unroll
    for (int off = 1; off < 64; off <<= 1) {
        int n = __shfl_up(inc, off);
        if (lane >= off) inc += n;
    }
    __shared__ int wsum[4];
    if (lane == 63) wsum[w] = inc;
    __syncthreads();
    int woff = 0;
#pragma unroll
    for (int i = 0; i < 4; ++i)
        if (i < w) woff += wsum[i];
    int ex = woff + inc - v;
    bbase[t] = ex;
    bcur[t] = ex;
}

// scatter edges into bucket-grouped packed array: u32 = (dst&255)<<16 | src
__global__ void __launch_bounds__(1024) bucket_scatter_kernel(const int* __restrict__ src,
                                                              const int* __restrict__ dst,
                                                              int* __restrict__ bcur,
                                                              uint* __restrict__ packed) {
    __shared__ int cnt[NBUK];
    __shared__ int base[NBUK];
    int t = threadIdx.x;
    long e0 = (long)blockIdx.x * 4096;
    for (int i = t; i < NBUK; i += 1024) cnt[i] = 0;
    __syncthreads();
    int b[4], off[4];
    uint pk[4];
#pragma unroll
    for (int u = 0; u < 4; ++u) {
        long e = e0 + u * 1024 + t;
        if (e < EE) {
            int d = dst[e];
            int s = src[e];
            b[u] = d >> 8;
            pk[u] = (uint)s | ((uint)(d & 255) << 16);
            off[u] = atomicAdd(&cnt[b[u]], 1);
        } else {
            b[u] = -1;
        }
    }
    __syncthreads();
    for (int i = t; i < NBUK; i += 1024) base[i] = cnt[i] ? atomicAdd(&bcur[i], cnt[i]) : 0;
    __syncthreads();
#pragma unroll
    for (int u = 0; u < 4; ++u)
        if (b[u] >= 0) packed[base[b[u]] + off[u]] = pk[u];
}

// one block per bucket: per-node degree hist + scan in LDS -> rowptr + sorted src (ushort)
__global__ void __launch_bounds__(1024) bucket_build_kernel(const uint* __restrict__ packed,
                                                            const int* __restrict__ bbase,
                                                            const int* __restrict__ bcnt,
                                                            int* __restrict__ rowptr,
                                                            ushort* __restrict__ sorted) {
    int b = blockIdx.x;
    int t = threadIdx.x;
    int ebeg = bbase[b], ecnt = bcnt[b];
    int node0 = b << 8;
    int nn = min(256, NN - node0);
    __shared__ int deg[256];
    __shared__ int cur[256];
    __shared__ int wsum[4];
    for (int i = t; i < 256; i += 1024) deg[i] = 0;
    __syncthreads();
    for (int i = t; i < ecnt; i += 1024) {
        uint p = packed[ebeg + i];
        atomicAdd(&deg[(p >> 16) & 255], 1);
    }
    __syncthreads();
    int lane = t & 63, w = t >> 6;
    int v = (t < 256) ? deg[t] : 0;
    int inc = v;
#pragma unroll
    for (int off = 1; off < 64; off <<= 1) {
        int n = __shfl_up(inc, off);
        if (lane >= off) inc += n;
    }
    if (t < 256 && lane == 63) wsum[w] = inc;
    __syncthreads();
    if (t < 256) {
        int woff = 0;
#pragma unroll
        for (int i = 0; i < 4; ++i)
            if (i < w) woff += wsum[i];
        int ex = woff + inc - v;
        if (t < nn) rowptr[node0 + t] = ebeg + ex;
        cur[t] = ebeg + ex;
    }
    if (b == NBUK - 1 && t == 0) rowptr[NN] = ebeg + ecnt;
    __syncthreads();
    for (int i = t; i < ecnt; i += 1024) {
        uint p = packed[ebeg + i];
        int pos = atomicAdd(&cur[(p >> 16) & 255], 1);
        sorted[pos] = (ushort)(p & 0xFFFFu);
    }
}

// ---------------- mean aggregation (R2 structure: wave/row, full-row, 8-deep pipeline) ----
// xu: bf16 table as uint (2 cols per lane); out: bf16 packed as uint
__global__ void __launch_bounds__(256) agg_kernel(const uint* __restrict__ xu,
                                                  const int* __restrict__ rowptr,
                                                  const ushort* __restrict__ srcs,
                                                  uint* __restrict__ out) {
    int wid = (blockIdx.x * blockDim.x + threadIdx.x) >> 6;
    int lane = threadIdx.x & 63;
    if (wid >= NN) return;
    int beg = rowptr[wid], end = rowptr[wid + 1];
    float ax = 0.f, ay = 0.f;
    int j = beg;
    int nfull = (end - beg) >> 3;
    int ss[8];
    if (nfull > 0) {
#pragma unroll
        for (int u = 0; u < 8; ++u) ss[u] = (int)srcs[j + u];
    }
    for (int ch = 0; ch < nfull; ++ch) {
        uint vv[8];
#pragma unroll
        for (int u = 0; u < 8; ++u) vv[u] = xu[ss[u] * 64 + lane];
        int base = j + 8;
        bool more = (ch + 1 < nfull);
        int sn[8];
#pragma unroll
        for (int u = 0; u < 8; ++u) sn[u] = more ? (int)srcs[base + u] : 0;
#pragma unroll
        for (int u = 0; u < 8; ++u) {
            ax += __uint_as_float(vv[u] << 16);
            ay += __uint_as_float(vv[u] & 0xffff0000u);
        }
#pragma unroll
        for (int u = 0; u < 8; ++u) ss[u] = sn[u];
        j += 8;
    }
    for (; j < end; ++j) {
        int s = (int)srcs[j];
        uint v = xu[s * 64 + lane];
        ax += __uint_as_float(v << 16);
        ay += __uint_as_float(v & 0xffff0000u);
    }
    float inv = (end > beg) ? 1.0f / (float)(end - beg) : 0.0f;
    uint lo = (uint)f2bf(ax * inv);
    uint hi = (uint)f2bf(ay * inv);
    out[(size_t)wid * 64 + lane] = lo | (hi << 16);
}

// ---------------- MFMA bf16 fused SAGE linear ----------------
// out = [relu](A1@W1 + A2@W2 + b); W given pre-transposed bf16 Wt[c][k].
// MODE 1: bf16 out + relu | MODE 2: layer2 + fused final linear -> [N,2] f32 (no relu)
// block 256 = 4 waves; block tile 64 rows; wave tile 16 rows x 128 cols.
// A-frag: lane l: row = l&15, k = (l>>4)*8 + j. B-frag: col = l&15, k = (l>>4)*8 + j.
// C-frag: col = l&15, row = (l>>4)*4 + reg.
template <int MODE>
__global__ void __launch_bounds__(256) mfma_gemm_kernel(
    const ushort* __restrict__ A1, const ushort* __restrict__ Wt1,
    const ushort* __restrict__ A2, const ushort* __restrict__ Wt2,
    const float* __restrict__ bias, const float* __restrict__ Wf,
    const float* __restrict__ bf, void* __restrict__ out) {
    int t = threadIdx.x;
    int wave = t >> 6, l = t & 63;
    int row0 = blockIdx.x * 64 + wave * 16;
    int lr = l & 15;   // A-row / B-col / C-col within tile
    int kq = l >> 4;   // k-quarter (8 bf16 each)

    f32x4 acc[8];
#pragma unroll
    for (int i = 0; i < 8; ++i) acc[i] = (f32x4){0.f, 0.f, 0.f, 0.f};

    int arow = row0 + lr;
    int safe = (arow < NN) ? arow : 0;  // clamp; garbage rows never stored
    const ushort* a1p = A1 + (size_t)safe * DD + kq * 8;
    const ushort* a2p = A2 + (size_t)safe * DD + kq * 8;

#pragma unroll
    for (int ks = 0; ks < 4; ++ks) {
        bf16x8 a1 = *(const bf16x8*)(a1p + ks * 32);
        bf16x8 a2 = *(const bf16x8*)(a2p + ks * 32);
#pragma unroll
        for (int ct = 0; ct < 8; ++ct) {
            bf16x8 b1 = *(const bf16x8*)(Wt1 + (size_t)(ct * 16 + lr) * DD + ks * 32 + kq * 8);
            acc[ct] = __builtin_amdgcn_mfma_f32_16x16x32_bf16(a1, b1, acc[ct], 0, 0, 0);
            bf16x8 b2 = *(const bf16x8*)(Wt2 + (size_t)(ct * 16 + lr) * DD + ks * 32 + kq * 8);
            acc[ct] = __builtin_amdgcn_mfma_f32_16x16x32_bf16(a2, b2, acc[ct], 0, 0, 0);
        }
    }

    if (MODE == 1) {
        // store bf16 with bias+relu: element (row = row0+kq*4+r, col = ct*16+lr)
        int crow = row0 + kq * 4;
#pragma unroll
        for (int ct = 0; ct < 8; ++ct) {
            float b = bias[ct * 16 + lr];
#pragma unroll
            for (int r = 0; r < 4; ++r) {
                int rr = crow + r;
                if (rr < NN) {
                    float v = fmaxf(acc[ct][r] + b, 0.f);
                    ((ushort*)out)[(size_t)rr * DD + ct * 16 + lr] = f2bf(v);
                }
            }
        }
    } else {
        // fused final linear: p[row][o] = sum_c (h + bias)[row][c] * Wf[c][o]; + bf[o]
        float s[4][2] = {{0.f, 0.f}, {0.f, 0.f}, {0.f, 0.f}, {0.f, 0.f}};
#pragma unroll
        for (int ct = 0; ct < 8; ++ct) {
            int c = ct * 16 + lr;
            float b = bias[c];
            float wf0 = Wf[c * 2 + 0], wf1 = Wf[c * 2 + 1];
#pragma unroll
            for (int r = 0; r < 4; ++r) {
                float v = acc[ct][r] + b;
                s[r][0] += v * wf0;
                s[r][1] += v * wf1;
            }
        }
        // reduce across the 16 col-lanes (lr); rows stay in (kq, r)
#pragma unroll
        for (int m = 1; m < 16; m <<= 1) {
#pragma unroll
            for (int r = 0; r < 4; ++r) {
                s[r][0] += __shfl_xor(s[r][0], m);
                s[r][1] += __shfl_xor(s[r][1], m);
            }
        }
        if (lr == 0) {
            int crow = row0 + kq * 4;
#pragma unroll
            for (int r = 0; r < 4; ++r) {
                int rr = crow + r;
                if (rr < NN) {
                    ((float*)out)[(size_t)rr * 2 + 0] = s[r][0] + bf[0];
                    ((float*)out)[(size_t)rr * 2 + 1] = s[r][1] + bf[1];
                }
            }
        }
    }
}

extern "C" void kernel_launch(void* const* d_in, const int* in_sizes, int n_in,
                              void* d_out, int out_size, void* d_ws, size_t ws_size,
                              hipStream_t stream) {
    const float* x_student = (const float*)d_in[0];
    const float* x_studies = (const float*)d_in[1];
    const int* ei_s2st = (const int*)d_in[2];
    const int* ei_st2s = (const int*)d_in[3];
    const float* l1_st_Wl = (const float*)d_in[4];
    const float* l1_st_b = (const float*)d_in[5];
    const float* l1_st_Wr = (const float*)d_in[6];
    const float* l1_s_Wl = (const float*)d_in[7];
    const float* l1_s_b = (const float*)d_in[8];
    const float* l1_s_Wr = (const float*)d_in[9];
    const float* l2_st_Wl = (const float*)d_in[10];
    const float* l2_st_b = (const float*)d_in[11];
    const float* l2_st_Wr = (const float*)d_in[12];
    const float* lin_W = (const float*)d_in[16];
    const float* lin_b = (const float*)d_in[17];
    float* out = (float*)d_out;

    // workspace layout (all bf16 feature tables)
    char* ws = (char*)d_ws;
    ushort* aggbuf = (ushort*)ws;                   // N*D bf16 (agg output, reused 3x)
    ushort* hst_bf = aggbuf + (size_t)NN * DD;      // N*D bf16
    ushort* hs_bf = hst_bf + (size_t)NN * DD;       // N*D bf16
    ushort* xstu_bf = hs_bf + (size_t)NN * DD;      // N*D bf16
    ushort* xsts_bf = xstu_bf + (size_t)NN * DD;    // N*D bf16
    ushort* Wt = xsts_bf + (size_t)NN * DD;         // 6 * 128*128 bf16 (transposed weights)
    uint* packed = (uint*)(Wt + 6 * DD * DD);       // E u32 (transient, shared a/b)
    int* rowptr_a = (int*)(packed + EE);            // N+1
    int* rowptr_b = rowptr_a + (NN + 1);            // N+1
    int* bcnt_a = rowptr_b + (NN + 1);              // 256
    int* bcnt_b = bcnt_a + 256;                     // 256
    int* bbase_a = bcnt_b + 256;                    // 256
    int* bcur_a = bbase_a + 256;                    // 256
    int* bbase_b = bcur_a + 256;                    // 256
    int* bcur_b = bbase_b + 256;                    // 256
    ushort* sorted_a = (ushort*)(bcur_b + 256);     // E ushort
    ushort* sorted_b = sorted_a + EE;               // E ushort

    const int* src_a = ei_s2st;       // s2st: src=student
    const int* dst_a = ei_s2st + EE;  // dst=studies
    const int* src_b = ei_st2s;       // st2s: src=studies
    const int* dst_b = ei_st2s + EE;  // dst=student

    const int cvGrid = (NN * DD / 4 + 255) / 256;
    const int scGrid = (EE + 4095) / 4096;      // 391
    const int aggGrid = (NN * 64 + 255) / 256;  // 12500 (wave per row)
    const int gemmGrid = (NN + 63) / 64;        // 782

    // 0. bf16 feature tables + transposed bf16 weights
    f32_to_bf16_kernel<<<cvGrid, 256, 0, stream>>>(x_student, xstu_bf, NN * DD / 4);
    f32_to_bf16_kernel<<<cvGrid, 256, 0, stream>>>(x_studies, xsts_bf, NN * DD / 4);
    wconv_kernel<<<64, 256, 0, stream>>>(l1_st_Wl, Wt + 0 * DD * DD);
    wconv_kernel<<<64, 256, 0, stream>>>(l1_st_Wr, Wt + 1 * DD * DD);
    wconv_kernel<<<64, 256, 0, stream>>>(l1_s_Wl, Wt + 2 * DD * DD);
    wconv_kernel<<<64, 256, 0, stream>>>(l1_s_Wr, Wt + 3 * DD * DD);
    wconv_kernel<<<64, 256, 0, stream>>>(l2_st_Wl, Wt + 4 * DD * DD);
    wconv_kernel<<<64, 256, 0, stream>>>(l2_st_Wr, Wt + 5 * DD * DD);

    // 1. bucketed CSR build, edge type a then b (shared packed buffer)
    (void)hipMemsetAsync(bcnt_a, 0, 2 * 256 * sizeof(int), stream);
    bucket_hist_kernel<<<256, 1024, 0, stream>>>(dst_a, bcnt_a);
    bucket_hist_kernel<<<256, 1024, 0, stream>>>(dst_b, bcnt_b);
    bucket_scan_kernel<<<1, 256, 0, stream>>>(bcnt_a, bbase_a, bcur_a);
    bucket_scan_kernel<<<1, 256, 0, stream>>>(bcnt_b, bbase_b, bcur_b);
    bucket_scatter_kernel<<<scGrid, 1024, 0, stream>>>(src_a, dst_a, bcur_a, packed);
    bucket_build_kernel<<<NBUK, 1024, 0, stream>>>(packed, bbase_a, bcnt_a, rowptr_a, sorted_a);
    bucket_scatter_kernel<<<scGrid, 1024, 0, stream>>>(src_b, dst_b, bcur_b, packed);
    bucket_build_kernel<<<NBUK, 1024, 0, stream>>>(packed, bbase_b, bcnt_b, rowptr_b, sorted_b);

    // 2. layer 1: h_st = relu(mean_s2st(x_student)@Wl + b + x_studies@Wr) -> bf16
    agg_kernel<<<aggGrid, 256, 0, stream>>>((const uint*)xstu_bf, rowptr_a, sorted_a,
                                            (uint*)aggbuf);
    mfma_gemm_kernel<1><<<gemmGrid, 256, 0, stream>>>(aggbuf, Wt + 0 * DD * DD, xsts_bf,
                                                      Wt + 1 * DD * DD, l1_st_b, nullptr,
                                                      nullptr, hst_bf);
    //    h_s = relu(mean_st2s(x_studies)@Wl + b + x_student@Wr) -> bf16
    agg_kernel<<<aggGrid, 256, 0, stream>>>((const uint*)xsts_bf, rowptr_b, sorted_b,
                                            (uint*)aggbuf);
    mfma_gemm_kernel<1><<<gemmGrid, 256, 0, stream>>>(aggbuf, Wt + 2 * DD * DD, xstu_bf,
                                                      Wt + 3 * DD * DD, l1_s_b, nullptr,
                                                      nullptr, hs_bf);

    // 3. layer 2 + fused final linear -> out [N,2]
    agg_kernel<<<aggGrid, 256, 0, stream>>>((const uint*)hs_bf, rowptr_a, sorted_a,
                                            (uint*)aggbuf);
    mfma_gemm_kernel<2><<<gemmGrid, 256, 0, stream>>>(aggbuf, Wt + 4 * DD * DD, hst_bf,
                                                      Wt + 5 * DD * DD, l2_st_b, lin_W, lin_b,
                                                      out);
}

// Round 13
// 483.238 us; speedup vs baseline: 2.0056x; 1.0438x over previous
//
#include <hip/hip_runtime.h>

#define NN 50000
#define DD 128
#define EE 1600000
#define NBUK 196   // ceil(50000/256) buckets of 256 nodes
#define NR 13      // src ranges (src>>12): 49999>>12 = 12 -> ranges 0..12
#define NKEY (256 * NR)  // 3328 sort keys per bucket

typedef unsigned int uint;
typedef unsigned short ushort;
typedef __attribute__((ext_vector_type(8))) short bf16x8;  // 8 bf16 = 4 VGPRs (MFMA A/B frag)
typedef __attribute__((ext_vector_type(4))) float f32x4;   // MFMA C/D frag

__device__ __forceinline__ ushort f2bf(float f) {
    uint u = __float_as_uint(f);
    u += 0x7fffu + ((u >> 16) & 1u);  // round-to-nearest-even
    return (ushort)(u >> 16);
}

// ---------------- f32 -> bf16 table conversion (both x tables in one dispatch) ----------
__global__ void __launch_bounds__(256) f32_to_bf16_kernel(const float* __restrict__ in0,
                                                          ushort* __restrict__ out0,
                                                          const float* __restrict__ in1,
                                                          ushort* __restrict__ out1, int n4) {
    int half = gridDim.x >> 1;
    const float* in = (blockIdx.x < half) ? in0 : in1;
    ushort* out = (blockIdx.x < half) ? out0 : out1;
    int bid = (blockIdx.x < half) ? blockIdx.x : blockIdx.x - half;
    int i = bid * 256 + threadIdx.x;
    if (i < n4) {
        float4 v = ((const float4*)in)[i];
        ushort4 o;
        o.x = f2bf(v.x);
        o.y = f2bf(v.y);
        o.z = f2bf(v.z);
        o.w = f2bf(v.w);
        ((ushort4*)out)[i] = o;
    }
}

// all 6 W [k][c] f32 -> Wt [c][k] bf16 in one dispatch (64 blocks per matrix)
__global__ void __launch_bounds__(256) wconv6_kernel(const float* __restrict__ w0,
                                                     const float* __restrict__ w1,
                                                     const float* __restrict__ w2,
                                                     const float* __restrict__ w3,
                                                     const float* __restrict__ w4,
                                                     const float* __restrict__ w5,
                                                     ushort* __restrict__ wt) {
    int m = blockIdx.x >> 6;
    const float* w;
    switch (m) {
        case 0: w = w0; break;
        case 1: w = w1; break;
        case 2: w = w2; break;
        case 3: w = w3; break;
        case 4: w = w4; break;
        default: w = w5; break;
    }
    int idx = (blockIdx.x & 63) * 256 + threadIdx.x;  // 0..16383
    int c = idx >> 7, k = idx & 127;
    wt[m * DD * DD + idx] = f2bf(w[k * DD + c]);
}

// ---------------- bucketed CSR build ----------------
// bucket b = dst >> 8 (256 nodes per bucket)

// both edge types in one dispatch: first half of grid -> dstA, second -> dstB
__global__ void __launch_bounds__(1024) bucket_hist_kernel(const int* __restrict__ dstA,
                                                           int* __restrict__ bcntA,
                                                           const int* __restrict__ dstB,
                                                           int* __restrict__ bcntB) {
    int half = gridDim.x >> 1;
    const int* dst = (blockIdx.x < half) ? dstA : dstB;
    int* bcnt = (blockIdx.x < half) ? bcntA : bcntB;
    int bid = (blockIdx.x < half) ? blockIdx.x : blockIdx.x - half;
    __shared__ int h[NBUK];
    int t = threadIdx.x;
    for (int i = t; i < NBUK; i += 1024) h[i] = 0;
    __syncthreads();
    for (int e = bid * 1024 + t; e < EE; e += half * 1024) atomicAdd(&h[dst[e] >> 8], 1);
    __syncthreads();
    for (int i = t; i < NBUK; i += 1024)
        if (h[i]) atomicAdd(&bcnt[i], h[i]);
}

// 2 blocks: block 0 scans bcntA, block 1 scans bcntB (256 entries each)
__global__ void __launch_bounds__(256) bucket_scan_kernel(const int* __restrict__ bcntA,
                                                          int* __restrict__ bbaseA,
                                                          int* __restrict__ bcurA,
                                                          const int* __restrict__ bcntB,
                                                          int* __restrict__ bbaseB,
                                                          int* __restrict__ bcurB) {
    const int* bcnt = (blockIdx.x == 0) ? bcntA : bcntB;
    int* bbase = (blockIdx.x == 0) ? bbaseA : bbaseB;
    int* bcur = (blockIdx.x == 0) ? bcurA : bcurB;
    int t = threadIdx.x, lane = t & 63, w = t >> 6;
    int v = bcnt[t];
    int inc = v;
#pragma unroll
    for (int off = 1; off < 64; off <<= 1) {
        int n = __shfl_up(inc, off);
        if (lane >= off) inc += n;
    }
    __shared__ int wsum[4];
    if (lane == 63) wsum[w] = inc;
    __syncthreads();
    int woff = 0;
#pragma unroll
    for (int i = 0; i < 4; ++i)
        if (i < w) woff += wsum[i];
    int ex = woff + inc - v;
    bbase[t] = ex;
    bcur[t] = ex;
}

// scatter edges into bucket-grouped packed array: u32 = (dst&255)<<16 | src
__global__ void __launch_bounds__(1024) bucket_scatter_kernel(const int* __restrict__ src,
                                                              const int* __restrict__ dst,
                                                              int* __restrict__ bcur,
                                                              uint* __restrict__ packed) {
    __shared__ int cnt[NBUK];
    __shared__ int base[NBUK];
    int t = threadIdx.x;
    long e0 = (long)blockIdx.x * 4096;
    for (int i = t; i < NBUK; i += 1024) cnt[i] = 0;
    __syncthreads();
    int b[4], off[4];
    uint pk[4];
#pragma unroll
    for (int u = 0; u < 4; ++u) {
        long e = e0 + u * 1024 + t;
        if (e < EE) {
            int d = dst[e];
            int s = src[e];
            b[u] = d >> 8;
            pk[u] = (uint)s | ((uint)(d & 255) << 16);
            off[u] = atomicAdd(&cnt[b[u]], 1);
        } else {
            b[u] = -1;
        }
    }
    __syncthreads();
    for (int i = t; i < NBUK; i += 1024) base[i] = cnt[i] ? atomicAdd(&bcur[i], cnt[i]) : 0;
    __syncthreads();
#pragma unroll
    for (int u = 0; u < 4; ++u)
        if (b[u] >= 0) packed[base[b[u]] + off[u]] = pk[u];
}

// one block per bucket: counting sort by key (dst_local, src_range) -> rowptr + sorted src.
// Range-sorted neighbor lists make concurrent agg waves traverse the same ~1MB table slice
// (soft lockstep) -> gather becomes L2-resident instead of 69% L2-miss.
__global__ void __launch_bounds__(1024) bucket_build_kernel(const uint* __restrict__ packed,
                                                            const int* __restrict__ bbase,
                                                            const int* __restrict__ bcnt,
                                                            int* __restrict__ rowptr,
                                                            ushort* __restrict__ sorted) {
    int b = blockIdx.x;
    int t = threadIdx.x;
    int ebeg = bbase[b], ecnt = bcnt[b];
    int node0 = b << 8;
    int nn = min(256, NN - node0);
    __shared__ int deg[NKEY];  // 3328
    __shared__ int cur[NKEY];
    __shared__ int wsum[16];
    for (int i = t; i < NKEY; i += 1024) deg[i] = 0;
    __syncthreads();
    for (int i = t; i < ecnt; i += 1024) {
        uint p = packed[ebeg + i];
        int key = (int)((p >> 16) & 255) * NR + (int)((p & 0xFFFFu) >> 12);
        atomicAdd(&deg[key], 1);
    }
    __syncthreads();
    // exclusive scan over NKEY: thread t owns slots [4t, 4t+4)
    int base4 = t * 4;
    int local[4];
    int s = 0;
#pragma unroll
    for (int k = 0; k < 4; ++k) {
        int v = (base4 + k < NKEY) ? deg[base4 + k] : 0;
        local[k] = s;
        s += v;
    }
    int lane = t & 63, w = t >> 6;
    int inc = s;
#pragma unroll
    for (int off = 1; off < 64; off <<= 1) {
        int n = __shfl_up(inc, off);
        if (lane >= off) inc += n;
    }
    if (lane == 63) wsum[w] = inc;
    __syncthreads();
    int woff = 0;
#pragma unroll
    for (int i = 0; i < 16; ++i)
        if (i < w) woff += wsum[i];
    int te = woff + inc - s;  // thread-exclusive
#pragma unroll
    for (int k = 0; k < 4; ++k)
        if (base4 + k < NKEY) cur[base4 + k] = ebeg + te + local[k];
    __syncthreads();
    // row start = start of key (row, range 0)
    if (t < nn) rowptr[node0 + t] = cur[t * NR];
    if (b == NBUK - 1 && t == 0) rowptr[NN] = ebeg + ecnt;
    __syncthreads();
    for (int i = t; i < ecnt; i += 1024) {
        uint p = packed[ebeg + i];
        int sv = (int)(p & 0xFFFFu);
        int key = (int)((p >> 16) & 255) * NR + (sv >> 12);
        int pos = atomicAdd(&cur[key], 1);
        sorted[pos] = (ushort)sv;
    }
}

// ---------------- mean aggregation (wave/row, full-row, 8-deep pipeline) ----------------
// xu: bf16 table as uint (2 cols per lane); out: bf16 packed as uint
__global__ void __launch_bounds__(256) agg_kernel(const uint* __restrict__ xu,
                                                  const int* __restrict__ rowptr,
                                                  const ushort* __restrict__ srcs,
                                                  uint* __restrict__ out) {
    int wid = (blockIdx.x * blockDim.x + threadIdx.x) >> 6;
    int lane = threadIdx.x & 63;
    if (wid >= NN) return;
    int beg = rowptr[wid], end = rowptr[wid + 1];
    float ax = 0.f, ay = 0.f;
    int j = beg;
    int nfull = (end - beg) >> 3;
    int ss[8];
    if (nfull > 0) {
#pragma unroll
        for (int u = 0; u < 8; ++u) ss[u] = (int)srcs[j + u];
    }
    for (int ch = 0; ch < nfull; ++ch) {
        uint vv[8];
#pragma unroll
        for (int u = 0; u < 8; ++u) vv[u] = xu[ss[u] * 64 + lane];
        int base = j + 8;
        bool more = (ch + 1 < nfull);
        int sn[8];
#pragma unroll
        for (int u = 0; u < 8; ++u) sn[u] = more ? (int)srcs[base + u] : 0;
#pragma unroll
        for (int u = 0; u < 8; ++u) {
            ax += __uint_as_float(vv[u] << 16);
            ay += __uint_as_float(vv[u] & 0xffff0000u);
        }
#pragma unroll
        for (int u = 0; u < 8; ++u) ss[u] = sn[u];
        j += 8;
    }
    for (; j < end; ++j) {
        int s = (int)srcs[j];
        uint v = xu[s * 64 + lane];
        ax += __uint_as_float(v << 16);
        ay += __uint_as_float(v & 0xffff0000u);
    }
    float inv = (end > beg) ? 1.0f / (float)(end - beg) : 0.0f;
    uint lo = (uint)f2bf(ax * inv);
    uint hi = (uint)f2bf(ay * inv);
    out[(size_t)wid * 64 + lane] = lo | (hi << 16);
}

// ---------------- MFMA bf16 fused SAGE linear ----------------
// out = [relu](A1@W1 + A2@W2 + b); W given pre-transposed bf16 Wt[c][k].
// MODE 1: bf16 out + relu | MODE 2: layer2 + fused final linear -> [N,2] f32 (no relu)
template <int MODE>
__global__ void __launch_bounds__(256) mfma_gemm_kernel(
    const ushort* __restrict__ A1, const ushort* __restrict__ Wt1,
    const ushort* __restrict__ A2, const ushort* __restrict__ Wt2,
    const float* __restrict__ bias, const float* __restrict__ Wf,
    const float* __restrict__ bf, void* __restrict__ out) {
    int t = threadIdx.x;
    int wave = t >> 6, l = t & 63;
    int row0 = blockIdx.x * 64 + wave * 16;
    int lr = l & 15;   // A-row / B-col / C-col within tile
    int kq = l >> 4;   // k-quarter (8 bf16 each)

    f32x4 acc[8];
#pragma unroll
    for (int i = 0; i < 8; ++i) acc[i] = (f32x4){0.f, 0.f, 0.f, 0.f};

    int arow = row0 + lr;
    int safe = (arow < NN) ? arow : 0;  // clamp; garbage rows never stored
    const ushort* a1p = A1 + (size_t)safe * DD + kq * 8;
    const ushort* a2p = A2 + (size_t)safe * DD + kq * 8;

#pragma unroll
    for (int ks = 0; ks < 4; ++ks) {
        bf16x8 a1 = *(const bf16x8*)(a1p + ks * 32);
        bf16x8 a2 = *(const bf16x8*)(a2p + ks * 32);
#pragma unroll
        for (int ct = 0; ct < 8; ++ct) {
            bf16x8 b1 = *(const bf16x8*)(Wt1 + (size_t)(ct * 16 + lr) * DD + ks * 32 + kq * 8);
            acc[ct] = __builtin_amdgcn_mfma_f32_16x16x32_bf16(a1, b1, acc[ct], 0, 0, 0);
            bf16x8 b2 = *(const bf16x8*)(Wt2 + (size_t)(ct * 16 + lr) * DD + ks * 32 + kq * 8);
            acc[ct] = __builtin_amdgcn_mfma_f32_16x16x32_bf16(a2, b2, acc[ct], 0, 0, 0);
        }
    }

    if (MODE == 1) {
        // store bf16 with bias+relu: element (row = row0+kq*4+r, col = ct*16+lr)
        int crow = row0 + kq * 4;
#pragma unroll
        for (int ct = 0; ct < 8; ++ct) {
            float b = bias[ct * 16 + lr];
#pragma unroll
            for (int r = 0; r < 4; ++r) {
                int rr = crow + r;
                if (rr < NN) {
                    float v = fmaxf(acc[ct][r] + b, 0.f);
                    ((ushort*)out)[(size_t)rr * DD + ct * 16 + lr] = f2bf(v);
                }
            }
        }
    } else {
        // fused final linear: p[row][o] = sum_c (h + bias)[row][c] * Wf[c][o]; + bf[o]
        float s[4][2] = {{0.f, 0.f}, {0.f, 0.f}, {0.f, 0.f}, {0.f, 0.f}};
#pragma unroll
        for (int ct = 0; ct < 8; ++ct) {
            int c = ct * 16 + lr;
            float b = bias[c];
            float wf0 = Wf[c * 2 + 0], wf1 = Wf[c * 2 + 1];
#pragma unroll
            for (int r = 0; r < 4; ++r) {
                float v = acc[ct][r] + b;
                s[r][0] += v * wf0;
                s[r][1] += v * wf1;
            }
        }
        // reduce across the 16 col-lanes (lr); rows stay in (kq, r)
#pragma unroll
        for (int m = 1; m < 16; m <<= 1) {
#pragma unroll
            for (int r = 0; r < 4; ++r) {
                s[r][0] += __shfl_xor(s[r][0], m);
                s[r][1] += __shfl_xor(s[r][1], m);
            }
        }
        if (lr == 0) {
            int crow = row0 + kq * 4;
#pragma unroll
            for (int r = 0; r < 4; ++r) {
                int rr = crow + r;
                if (rr < NN) {
                    ((float*)out)[(size_t)rr * 2 + 0] = s[r][0] + bf[0];
                    ((float*)out)[(size_t)rr * 2 + 1] = s[r][1] + bf[1];
                }
            }
        }
    }
}

extern "C" void kernel_launch(void* const* d_in, const int* in_sizes, int n_in,
                              void* d_out, int out_size, void* d_ws, size_t ws_size,
                              hipStream_t stream) {
    const float* x_student = (const float*)d_in[0];
    const float* x_studies = (const float*)d_in[1];
    const int* ei_s2st = (const int*)d_in[2];
    const int* ei_st2s = (const int*)d_in[3];
    const float* l1_st_Wl = (const float*)d_in[4];
    const float* l1_st_b = (const float*)d_in[5];
    const float* l1_st_Wr = (const float*)d_in[6];
    const float* l1_s_Wl = (const float*)d_in[7];
    const float* l1_s_b = (const float*)d_in[8];
    const float* l1_s_Wr = (const float*)d_in[9];
    const float* l2_st_Wl = (const float*)d_in[10];
    const float* l2_st_b = (const float*)d_in[11];
    const float* l2_st_Wr = (const float*)d_in[12];
    const float* lin_W = (const float*)d_in[16];
    const float* lin_b = (const float*)d_in[17];
    float* out = (float*)d_out;

    // workspace layout (all bf16 feature tables)
    char* ws = (char*)d_ws;
    ushort* aggbuf = (ushort*)ws;                   // N*D bf16 (agg output, reused 3x)
    ushort* hst_bf = aggbuf + (size_t)NN * DD;      // N*D bf16
    ushort* hs_bf = hst_bf + (size_t)NN * DD;       // N*D bf16
    ushort* xstu_bf = hs_bf + (size_t)NN * DD;      // N*D bf16
    ushort* xsts_bf = xstu_bf + (size_t)NN * DD;    // N*D bf16
    ushort* Wt = xsts_bf + (size_t)NN * DD;         // 6 * 128*128 bf16 (transposed weights)
    uint* packed = (uint*)(Wt + 6 * DD * DD);       // E u32 (transient, shared a/b)
    int* rowptr_a = (int*)(packed + EE);            // N+1
    int* rowptr_b = rowptr_a + (NN + 1);            // N+1
    int* bcnt_a = rowptr_b + (NN + 1);              // 256
    int* bcnt_b = bcnt_a + 256;                     // 256
    int* bbase_a = bcnt_b + 256;                    // 256
    int* bcur_a = bbase_a + 256;                    // 256
    int* bbase_b = bcur_a + 256;                    // 256
    int* bcur_b = bbase_b + 256;                    // 256
    ushort* sorted_a = (ushort*)(bcur_b + 256);     // E ushort
    ushort* sorted_b = sorted_a + EE;               // E ushort

    const int* src_a = ei_s2st;       // s2st: src=student
    const int* dst_a = ei_s2st + EE;  // dst=studies
    const int* src_b = ei_st2s;       // st2s: src=studies
    const int* dst_b = ei_st2s + EE;  // dst=student

    const int cvGrid = (NN * DD / 4 + 255) / 256;  // per table
    const int scGrid = (EE + 4095) / 4096;         // 391
    const int aggGrid = (NN * 64 + 255) / 256;     // 12500 (wave per row)
    const int gemmGrid = (NN + 63) / 64;           // 782

    // 0. bf16 feature tables + transposed bf16 weights (fused dispatches)
    f32_to_bf16_kernel<<<2 * cvGrid, 256, 0, stream>>>(x_student, xstu_bf, x_studies, xsts_bf,
                                                       NN * DD / 4);
    wconv6_kernel<<<6 * 64, 256, 0, stream>>>(l1_st_Wl, l1_st_Wr, l1_s_Wl, l1_s_Wr, l2_st_Wl,
                                              l2_st_Wr, Wt);

    // 1. bucketed CSR build (src-range-sorted), edge type a then b (shared packed buffer)
    (void)hipMemsetAsync(bcnt_a, 0, 2 * 256 * sizeof(int), stream);
    bucket_hist_kernel<<<512, 1024, 0, stream>>>(dst_a, bcnt_a, dst_b, bcnt_b);
    bucket_scan_kernel<<<2, 256, 0, stream>>>(bcnt_a, bbase_a, bcur_a, bcnt_b, bbase_b, bcur_b);
    bucket_scatter_kernel<<<scGrid, 1024, 0, stream>>>(src_a, dst_a, bcur_a, packed);
    bucket_build_kernel<<<NBUK, 1024, 0, stream>>>(packed, bbase_a, bcnt_a, rowptr_a, sorted_a);
    bucket_scatter_kernel<<<scGrid, 1024, 0, stream>>>(src_b, dst_b, bcur_b, packed);
    bucket_build_kernel<<<NBUK, 1024, 0, stream>>>(packed, bbase_b, bcnt_b, rowptr_b, sorted_b);

    // 2. layer 1: h_st = relu(mean_s2st(x_student)@Wl + b + x_studies@Wr) -> bf16
    agg_kernel<<<aggGrid, 256, 0, stream>>>((const uint*)xstu_bf, rowptr_a, sorted_a,
                                            (uint*)aggbuf);
    mfma_gemm_kernel<1><<<gemmGrid, 256, 0, stream>>>(aggbuf, Wt + 0 * DD * DD, xsts_bf,
                                                      Wt + 1 * DD * DD, l1_st_b, nullptr,
                                                      nullptr, hst_bf);
    //    h_s = relu(mean_st2s(x_studies)@Wl + b + x_student@Wr) -> bf16
    agg_kernel<<<aggGrid, 256, 0, stream>>>((const uint*)xsts_bf, rowptr_b, sorted_b,
                                            (uint*)aggbuf);
    mfma_gemm_kernel<1><<<gemmGrid, 256, 0, stream>>>(aggbuf, Wt + 2 * DD * DD, xstu_bf,
                                                      Wt + 3 * DD * DD, l1_s_b, nullptr,
                                                      nullptr, hs_bf);

    // 3. layer 2 + fused final linear -> out [N,2]
    agg_kernel<<<aggGrid, 256, 0, stream>>>((const uint*)hs_bf, rowptr_a, sorted_a,
                                            (uint*)aggbuf);
    mfma_gemm_kernel<2><<<gemmGrid, 256, 0, stream>>>(aggbuf, Wt + 4 * DD * DD, hst_bf,
                                                      Wt + 5 * DD * DD, l2_st_b, lin_W, lin_b,
                                                      out);
}